// Round 1
// 555.723 us; speedup vs baseline: 1.2006x; 1.2006x over previous
//
#include <hip/hip_runtime.h>
#include <math.h>

#define DIM 512
#define KQn 4
#define HQ  32
#define BB  16
#define NN  8192
#define EPSLN 1e-6f
#define TROWS  32

typedef _Float16 f16;
typedef _Float16 h2_t __attribute__((ext_vector_type(2)));
typedef __fp16   g2_t __attribute__((ext_vector_type(2)));
typedef _Float16 h8_t __attribute__((ext_vector_type(8)));
typedef float    f32x4 __attribute__((ext_vector_type(4)));

union U32H2 { unsigned int u; h2_t h; g2_t g; };
union U4H8  { uint4 u; h8_t h; unsigned int w[4]; };

__device__ inline unsigned int pkh2(float a, float b) {
    U32H2 v; v.g = __builtin_amdgcn_cvt_pkrtz(a, b); return v.u;
}
__device__ inline h2_t ash2(unsigned int u) { U32H2 v; v.u = u; return v.h; }

#if __has_builtin(__builtin_amdgcn_fdot2)
__device__ inline float fdot2f(unsigned int a, unsigned int b, float c) {
    return __builtin_amdgcn_fdot2(ash2(a), ash2(b), c, false);
}
#else
__device__ inline float fdot2f(unsigned int a, unsigned int b, float c) {
    h2_t ha = ash2(a), hb = ash2(b);
    return c + (float)ha.x*(float)hb.x + (float)ha.y*(float)hb.y;
}
#endif

// ---------------- K1a: q[hq][d] = seed[j] @ Wq[head h].T + bq ----------------
__global__ __launch_bounds__(256) void k_q(
    const float* __restrict__ seed, const float* __restrict__ Wq,
    const float* __restrict__ bq, float* __restrict__ q_g)
{
    int hq = blockIdx.x; int h = hq >> 2; int j = hq & 3;
    int t = threadIdx.x;
    __shared__ float qpart[256];
    int d = t >> 2, q4 = t & 3;
    const float* sr = seed + j*DIM + q4*128;
    const float* wr = Wq + (size_t)(h*64 + d)*DIM + q4*128;
    float acc = 0.f;
    for (int c = 0; c < 128; c += 4) {
        float4 s4 = *(const float4*)(sr + c);
        float4 w4 = *(const float4*)(wr + c);
        acc += s4.x*w4.x + s4.y*w4.y + s4.z*w4.z + s4.w*w4.w;
    }
    qpart[t] = acc;
    __syncthreads();
    if (t < 64)
        q_g[hq*64 + t] = qpart[t*4] + qpart[t*4+1] + qpart[t*4+2] + qpart[t*4+3] + bq[h*64 + t];
}

// ---------------- K1b: qkB = MFMA-fragment-packed (q @ Wk_head)/8, fp16 ----------------
// B-fragment for v_mfma_f32_16x16x32_f16: lane l holds B[kb*32 + 8*(l>>4)+i][nb*16 + (l&15)].
// Packed so each lane's 8 halves are one contiguous 16B load:
//   qkB[ ((kb*2 + nb)*64 + lane)*8 + i ]
__global__ __launch_bounds__(256) void k_qk(
    const float* __restrict__ Wk, const float* __restrict__ q_g, f16* __restrict__ qkB)
{
    const int h = blockIdx.x;    // 0..7
    const int cs = blockIdx.y;   // 0..3
    const int t = threadIdx.x;
    __shared__ float q_s[4][64];
    __shared__ float red2[4][128];
    q_s[t >> 6][t & 63] = q_g[(h*4 + (t >> 6))*64 + (t & 63)];
    __syncthreads();
    const int c = cs*128 + (t & 127);
    const int dh = t >> 7;
    float a0=0.f, a1=0.f, a2=0.f, a3=0.f;
    const float* wb = Wk + ((size_t)(h*64 + dh*32))*DIM + c;
    #pragma unroll 8
    for (int d = 0; d < 32; ++d) {
        float w = wb[(size_t)d*DIM];                // coalesced across lanes
        a0 += q_s[0][dh*32 + d]*w;
        a1 += q_s[1][dh*32 + d]*w;
        a2 += q_s[2][dh*32 + d]*w;
        a3 += q_s[3][dh*32 + d]*w;
    }
    if (dh == 1) {
        red2[0][t & 127] = a0; red2[1][t & 127] = a1;
        red2[2][t & 127] = a2; red2[3][t & 127] = a3;
    }
    __syncthreads();
    if (dh == 0) {
        int ci = t & 127;
        float v[4];
        v[0] = (a0 + red2[0][ci]) * 0.125f;
        v[1] = (a1 + red2[1][ci]) * 0.125f;
        v[2] = (a2 + red2[2][ci]) * 0.125f;
        v[3] = (a3 + red2[3][ci]) * 0.125f;
        const int kb = c >> 5, g = (c >> 3) & 3, ii = c & 7;
        #pragma unroll
        for (int j = 0; j < 4; ++j) {
            const int hq = h*4 + j;
            const int nb = hq >> 4, lane = g*16 + (hq & 15);
            qkB[(((size_t)(kb*2 + nb)*64 + lane) << 3) + ii] = (f16)v[j];
        }
    }
}

// ---------------- K2: fused scores(MFMA) -> exp -> pool partials, one pass over X ----------------
// block = (chunk of crows rows, b), 256 threads = 4 waves.
// Per 32-row tile:
//   barrier; { stage X tile fp16 [c][n-pairs] into LDS  ||  phase A: MFMA scores from
//   global X + qkB, exp -> p_s };  barrier;  phase B: o[hq][c] += p*X via v_dot2.
// LDS 40.2 KB -> 4 blocks/CU.
__global__ __launch_bounds__(256, 4) void k_att(
    const float* __restrict__ X, const f16* __restrict__ qkB,
    f16* __restrict__ opart, float* __restrict__ lpart,
    int nchunk, int crows, int ntile)
{
    const int chunk = blockIdx.x, b = blockIdx.y;
    const int t = threadIdx.x;

    __shared__ f16 Xcm[512][36];      // [c][n] fp16, dword d of row c holds n=2d,2d+1
    __shared__ f16 p_s[32][36];       // [hq][n] fp16
    __shared__ float lred[256];       // per-lane l partials at end

    unsigned int* XcmU = (unsigned int*)&Xcm[0][0];   // row stride 18 dwords
    unsigned int* pW   = (unsigned int*)&p_s[0][0];

    const int w    = t >> 6;          // wave id
    const int lane = t & 63;
    const int mb = w & 1, nb = w >> 1; // phase A: row-half / hq-half of this wave
    const int lg = lane >> 4;          // 0..3
    const int lm = lane & 15;

    const int rp = t >> 4;            // staging row-pair
    const int cq = (t & 15) << 1;     // staging c offset

    const int hg = t >> 5;            // phase B: 4 hq at hg*4
    const int cg = t & 31;            // phase B: c lane

    float o_acc[4][16];
    #pragma unroll
    for (int j = 0; j < 4; ++j)
        #pragma unroll
        for (int i = 0; i < 16; ++i) o_acc[j][i] = 0.f;
    float l_local = 0.f;

    const size_t xbase = (size_t)b*NN*DIM;
    const uint4* qkB4 = (const uint4*)qkB;

    for (int tile = 0; tile < ntile; ++tile) {
        const int r0 = chunk*crows + tile*TROWS;
        __syncthreads();   // prev tile's phase B done before overwriting Xcm/p_s
        // ---- stage X tile (32 rows x 512 c) as fp16 [c][n] ----
        {
            const float2* Xr0 = (const float2*)(X + xbase + (size_t)(r0 + rp*2    )*DIM);
            const float2* Xr1 = (const float2*)(X + xbase + (size_t)(r0 + rp*2 + 1)*DIM);
            #pragma unroll
            for (int cs = 0; cs < 16; ++cs) {
                int c0 = cs*32 + cq;
                float2 xa = Xr0[c0 >> 1];
                float2 xb = Xr1[c0 >> 1];
                XcmU[c0*18 + rp]     = pkh2(xa.x, xb.x);
                XcmU[(c0+1)*18 + rp] = pkh2(xa.y, xb.y);
            }
        }
        // ---- phase A: S[32r][32hq] = Xtile @ QK via MFMA 16x16x32 f16 ----
        // A-frag: lane holds X[r0+mb*16+lm][kb*32 + lg*8 .. +7] (from global, lines warm)
        // B-frag: qkB pre-packed. D: row = mb*16 + 4*lg + reg, col hq = nb*16 + lm.
        {
            const float* xr = X + xbase + (size_t)(r0 + mb*16 + lm)*DIM + lg*8;
            f32x4 acc0 = {0.f,0.f,0.f,0.f}, acc1 = {0.f,0.f,0.f,0.f};
            #pragma unroll
            for (int kb = 0; kb < 16; ++kb) {
                float4 a0 = *(const float4*)(xr + kb*32);
                float4 a1 = *(const float4*)(xr + kb*32 + 4);
                U4H8 af;
                af.w[0] = pkh2(a0.x, a0.y); af.w[1] = pkh2(a0.z, a0.w);
                af.w[2] = pkh2(a1.x, a1.y); af.w[3] = pkh2(a1.z, a1.w);
                U4H8 bf; bf.u = qkB4[(size_t)(kb*2 + nb)*64 + lane];
                if (kb & 1) acc1 = __builtin_amdgcn_mfma_f32_16x16x32_f16(af.h, bf.h, acc1, 0, 0, 0);
                else        acc0 = __builtin_amdgcn_mfma_f32_16x16x32_f16(af.h, bf.h, acc0, 0, 0, 0);
            }
            float p0 = __expf(fminf(acc0[0] + acc1[0], 30.f));
            float p1 = __expf(fminf(acc0[1] + acc1[1], 30.f));
            float p2 = __expf(fminf(acc0[2] + acc1[2], 30.f));
            float p3 = __expf(fminf(acc0[3] + acc1[3], 30.f));
            l_local += p0 + p1 + p2 + p3;
            const int pidx = (nb*16 + lm)*18 + mb*8 + lg*2;   // even -> 8B aligned
            pW[pidx]     = pkh2(p0, p1);
            pW[pidx + 1] = pkh2(p2, p3);
        }
        __syncthreads();
        // ---- phase B: o[hq][c] += p[hq][n]*X[n][c] via v_dot2_f32_f16 ----
        {
            const unsigned int* pU = (const unsigned int*)&p_s[0][0];
            #pragma unroll
            for (int ng = 0; ng < 4; ++ng) {
                unsigned int pd[4][4];
                #pragma unroll
                for (int j = 0; j < 4; ++j) {
                    uint2 pa = *(const uint2*)&pU[(hg*4 + j)*18 + ng*4];
                    uint2 pb = *(const uint2*)&pU[(hg*4 + j)*18 + ng*4 + 2];
                    pd[j][0] = pa.x; pd[j][1] = pa.y; pd[j][2] = pb.x; pd[j][3] = pb.y;
                }
                #pragma unroll
                for (int mm = 0; mm < 4; ++mm) {
                    #pragma unroll
                    for (int cc = 0; cc < 4; ++cc) {
                        const int c = cg + mm*32 + cc*128;
                        const int ci = mm*4 + cc;
                        const unsigned int* row = &XcmU[c*18 + ng*4];
                        uint2 xa = *(const uint2*)&row[0];
                        uint2 xb = *(const uint2*)&row[2];
                        #pragma unroll
                        for (int j = 0; j < 4; ++j) {
                            float a = o_acc[j][ci];
                            a = fdot2f(pd[j][0], xa.x, a);
                            a = fdot2f(pd[j][1], xa.y, a);
                            a = fdot2f(pd[j][2], xb.x, a);
                            a = fdot2f(pd[j][3], xb.y, a);
                            o_acc[j][ci] = a;
                        }
                    }
                }
            }
        }
    }
    // ---- block totals: l and fp16 o partials (no atomics) ----
    __syncthreads();
    lred[w*64 + lane] = l_local;
    __syncthreads();
    if (t < 32) {
        const int nb2 = t >> 4, col = t & 15;
        float l = 0.f;
        #pragma unroll
        for (int mm = 0; mm < 2; ++mm)
            #pragma unroll
            for (int g = 0; g < 4; ++g)
                l += lred[(nb2*2 + mm)*64 + g*16 + col];
        lpart[((size_t)b*nchunk + chunk)*HQ + t] = l;
    }
    const size_t obase = (((size_t)b*nchunk + chunk)*HQ + hg*4)*DIM + cg;
    #pragma unroll
    for (int j = 0; j < 4; ++j)
        #pragma unroll
        for (int mm = 0; mm < 4; ++mm)
            #pragma unroll
            for (int cc = 0; cc < 4; ++cc)
                opart[obase + (size_t)j*DIM + mm*32 + cc*128] = (f16)o_acc[j][mm*4 + cc];
}

// ---------------- K3: reduce partials, normalize, fused Wv slice ----------------
__global__ __launch_bounds__(256) void k_red(
    const f16* __restrict__ opart, const float* __restrict__ lpart,
    const float* __restrict__ Wv, const float* __restrict__ bv,
    float* __restrict__ vbuf, int nchunk)
{
    const int hq = blockIdx.x, b = blockIdx.y;
    const int h = hq >> 2, j = hq & 3;
    const int t = threadIdx.x;
    __shared__ float pool_s[512];
    __shared__ float ls[64];
    __shared__ float linv_s;
    if (t < nchunk) ls[t] = lpart[((size_t)b*nchunk + t)*HQ + hq];
    __syncthreads();
    if (t == 0) {
        float l = 0.f;
        for (int i = 0; i < nchunk; ++i) l += ls[i];
        linv_s = 1.f / l;
    }
    float a0 = 0.f, a1 = 0.f;
    const unsigned int* opU = (const unsigned int*)opart;
    #pragma unroll 4
    for (int ch = 0; ch < nchunk; ++ch) {
        unsigned int u = opU[((((size_t)b*nchunk + ch)*HQ + hq) << 8) + t];
        h2_t hv = ash2(u);
        a0 += (float)hv.x; a1 += (float)hv.y;
    }
    __syncthreads();
    float linv = linv_s;
    pool_s[2*t]   = a0 * linv;
    pool_s[2*t+1] = a1 * linv;
    __syncthreads();
    const int o1 = t >> 2, q4 = t & 3;
    const float* wr = Wv + ((size_t)(h*64 + o1))*DIM + q4*128;
    const float* ps = pool_s + q4*128;
    float acc = 0.f;
    #pragma unroll 8
    for (int c = 0; c < 128; c += 4) {
        float4 w4 = *(const float4*)(wr + c);
        float4 p4 = *(const float4*)(ps + c);
        acc += w4.x*p4.x + w4.y*p4.y + w4.z*p4.z + w4.w*p4.w;
    }
    acc += __shfl_xor(acc, 1);
    acc += __shfl_xor(acc, 2);
    if (q4 == 0)
        vbuf[((size_t)b*KQn + j)*DIM + h*64 + o1] = acc + bv[h*64 + o1];
}

// ---------------- K4: Wo proj + residual + LayerNorm ----------------
__global__ __launch_bounds__(512) void k_wo_ln(
    const float* __restrict__ vbuf, const float* __restrict__ Wo, const float* __restrict__ bo,
    const float* __restrict__ seed, const float* __restrict__ gamma, const float* __restrict__ beta,
    float* __restrict__ out)
{
    const int j = blockIdx.x, b = blockIdx.y;
    const int t = threadIdx.x;
    __shared__ float v_s[512];
    __shared__ float wsum[8], wsq[8];
    v_s[t] = vbuf[((size_t)b*KQn + j)*DIM + t];
    __syncthreads();
    const float* wr = Wo + (size_t)t*DIM;
    float acc = bo[t];
    #pragma unroll 8
    for (int c = 0; c < 512; c += 4) {
        float4 w4 = *(const float4*)(wr + c);
        float4 p4 = *(const float4*)&v_s[c];
        acc += w4.x*p4.x + w4.y*p4.y + w4.z*p4.z + w4.w*p4.w;
    }
    float hv = acc + seed[j*DIM + t];
    float s1 = hv, s2 = hv*hv;
    #pragma unroll
    for (int m = 1; m <= 32; m <<= 1) {
        s1 += __shfl_xor(s1, m);
        s2 += __shfl_xor(s2, m);
    }
    if ((t & 63) == 0) { wsum[t >> 6] = s1; wsq[t >> 6] = s2; }
    __syncthreads();
    float tm = 0.f, tq = 0.f;
    #pragma unroll
    for (int i = 0; i < 8; ++i) { tm += wsum[i]; tq += wsq[i]; }
    float mu = tm * (1.f/512.f);
    float var = tq * (1.f/512.f) - mu*mu;
    float rs = rsqrtf(var + EPSLN);
    out[((size_t)b*KQn + j)*DIM + t] = (hv - mu)*rs*gamma[t] + beta[t];
}

extern "C" void kernel_launch(void* const* d_in, const int* in_sizes, int n_in,
                              void* d_out, int out_size, void* d_ws, size_t ws_size,
                              hipStream_t stream) {
    const float* X     = (const float*)d_in[0];
    const float* seed  = (const float*)d_in[1];
    const float* Wq    = (const float*)d_in[2];
    const float* bq    = (const float*)d_in[3];
    const float* Wk    = (const float*)d_in[4];
    // d_in[5] = bk : cancels in softmax, unused
    const float* Wv    = (const float*)d_in[6];
    const float* bv    = (const float*)d_in[7];
    const float* Wo    = (const float*)d_in[8];
    const float* bo    = (const float*)d_in[9];
    const float* gamma = (const float*)d_in[10];
    const float* beta  = (const float*)d_in[11];

    // choose chunk count by available workspace (64 -> 4 blocks/CU occupancy)
    int nchunk = 64;
    {
        const size_t need64 = 303104UL + (size_t)BB*64*HQ*DIM*2;   // ~33.9 MB
        if (ws_size < need64) nchunk = 32;                          // ~17.0 MB (prev layout)
    }
    const int crows = NN / nchunk;
    const int ntile = crows / TROWS;

    char* ws = (char*)d_ws;
    float* q_g   = (float*)(ws + 0);                 //  8192 B
    f16*   qkB   = (f16*)  (ws + 8192);              // 32768 B
    size_t off_lpart = 40960;
    size_t off_vbuf  = off_lpart + (size_t)BB*nchunk*HQ*4;
    size_t off_opart = off_vbuf + (size_t)BB*KQn*DIM*4;
    float* lpart = (float*)(ws + off_lpart);
    float* vbuf  = (float*)(ws + off_vbuf);
    f16*   opart = (f16*)  (ws + off_opart);
    float* out   = (float*)d_out;

    k_q    <<<32,               256, 0, stream>>>(seed, Wq, bq, q_g);
    k_qk   <<<dim3(8, 4),       256, 0, stream>>>(Wk, q_g, qkB);
    k_att  <<<dim3(nchunk, BB), 256, 0, stream>>>(X, qkB, opart, lpart, nchunk, crows, ntile);
    k_red  <<<dim3(HQ, BB),     256, 0, stream>>>(opart, lpart, Wv, bv, vbuf, nchunk);
    k_wo_ln<<<dim3(KQn, BB),    512, 0, stream>>>(vbuf, Wo, bo, seed, gamma, beta, out);
}

// Round 2
// 536.545 us; speedup vs baseline: 1.2435x; 1.0357x over previous
//
#include <hip/hip_runtime.h>
#include <math.h>

#define DIM 512
#define KQn 4
#define HQ  32
#define BB  16
#define NN  8192
#define EPSLN 1e-6f
#define TROWS  32

typedef _Float16 f16;
typedef _Float16 h2_t __attribute__((ext_vector_type(2)));
typedef __fp16   g2_t __attribute__((ext_vector_type(2)));
typedef _Float16 h8_t __attribute__((ext_vector_type(8)));
typedef float    f32x4 __attribute__((ext_vector_type(4)));

union U32H2 { unsigned int u; h2_t h; g2_t g; };
union U4H8  { uint4 u; h8_t h; unsigned int w[4]; };

__device__ inline unsigned int pkh2(float a, float b) {
    U32H2 v; v.g = __builtin_amdgcn_cvt_pkrtz(a, b); return v.u;
}
__device__ inline h2_t ash2(unsigned int u) { U32H2 v; v.u = u; return v.h; }

// ---------------- K1a: q[hq][d] = seed[j] @ Wq[head h].T + bq ----------------
__global__ __launch_bounds__(256) void k_q(
    const float* __restrict__ seed, const float* __restrict__ Wq,
    const float* __restrict__ bq, float* __restrict__ q_g)
{
    int hq = blockIdx.x; int h = hq >> 2; int j = hq & 3;
    int t = threadIdx.x;
    __shared__ float qpart[256];
    int d = t >> 2, q4 = t & 3;
    const float* sr = seed + j*DIM + q4*128;
    const float* wr = Wq + (size_t)(h*64 + d)*DIM + q4*128;
    float acc = 0.f;
    for (int c = 0; c < 128; c += 4) {
        float4 s4 = *(const float4*)(sr + c);
        float4 w4 = *(const float4*)(wr + c);
        acc += s4.x*w4.x + s4.y*w4.y + s4.z*w4.z + s4.w*w4.w;
    }
    qpart[t] = acc;
    __syncthreads();
    if (t < 64)
        q_g[hq*64 + t] = qpart[t*4] + qpart[t*4+1] + qpart[t*4+2] + qpart[t*4+3] + bq[h*64 + t];
}

// ---------------- K1b: qkB = MFMA-fragment-packed (q @ Wk_head)/8, fp16 ----------------
// B-fragment for v_mfma_f32_16x16x32_f16: lane l holds B[kb*32 + 8*(l>>4)+i][nb*16 + (l&15)].
__global__ __launch_bounds__(256) void k_qk(
    const float* __restrict__ Wk, const float* __restrict__ q_g, f16* __restrict__ qkB)
{
    const int h = blockIdx.x;    // 0..7
    const int cs = blockIdx.y;   // 0..3
    const int t = threadIdx.x;
    __shared__ float q_s[4][64];
    __shared__ float red2[4][128];
    q_s[t >> 6][t & 63] = q_g[(h*4 + (t >> 6))*64 + (t & 63)];
    __syncthreads();
    const int c = cs*128 + (t & 127);
    const int dh = t >> 7;
    float a0=0.f, a1=0.f, a2=0.f, a3=0.f;
    const float* wb = Wk + ((size_t)(h*64 + dh*32))*DIM + c;
    #pragma unroll 8
    for (int d = 0; d < 32; ++d) {
        float w = wb[(size_t)d*DIM];                // coalesced across lanes
        a0 += q_s[0][dh*32 + d]*w;
        a1 += q_s[1][dh*32 + d]*w;
        a2 += q_s[2][dh*32 + d]*w;
        a3 += q_s[3][dh*32 + d]*w;
    }
    if (dh == 1) {
        red2[0][t & 127] = a0; red2[1][t & 127] = a1;
        red2[2][t & 127] = a2; red2[3][t & 127] = a3;
    }
    __syncthreads();
    if (dh == 0) {
        int ci = t & 127;
        float v[4];
        v[0] = (a0 + red2[0][ci]) * 0.125f;
        v[1] = (a1 + red2[1][ci]) * 0.125f;
        v[2] = (a2 + red2[2][ci]) * 0.125f;
        v[3] = (a3 + red2[3][ci]) * 0.125f;
        const int kb = c >> 5, g = (c >> 3) & 3, ii = c & 7;
        #pragma unroll
        for (int j = 0; j < 4; ++j) {
            const int hq = h*4 + j;
            const int nb = hq >> 4, lane = g*16 + (hq & 15);
            qkB[(((size_t)(kb*2 + nb)*64 + lane) << 3) + ii] = (f16)v[j];
        }
    }
}

// ---------------- K2: fused scores(MFMA) -> exp -> pool(MFMA) partials ----------------
// block = (chunk of crows rows, b), 256 threads = 4 waves.
// Per 32-row tile:
//   barrier; { stage X fp16 [c][n-pairs] into LDS || phase A: MFMA scores from global X
//   + qkB, exp -> p_s[hq][n] }; barrier; phase B: D[c][hq] = X^T @ p via MFMA
//   (A-frag = Xcm rows (contiguous n!), B-frag = p_s rows (contiguous n!)).
// Epilogue: o_acc (c-major) -> LDS transpose -> coalesced [hq][c] opart write.
// LDS 40448 B -> 4 blocks/CU.
__global__ __launch_bounds__(256, 4) void k_att(
    const float* __restrict__ X, const f16* __restrict__ qkB,
    f16* __restrict__ opart, float* __restrict__ lpart,
    int nchunk, int crows, int ntile)
{
    const int chunk = blockIdx.x, b = blockIdx.y;
    const int t = threadIdx.x;

    __shared__ f16 Xcm[512][36];      // [c][n] fp16, dword d of row c holds n=2d,2d+1
    __shared__ f16 p_s[32][40];       // [hq][n] fp16, stride 40 (20 dwords, 16B-aligned rows)
    __shared__ float lred[256];

    unsigned int* XcmU = (unsigned int*)&Xcm[0][0];   // row stride 18 dwords
    unsigned int* pW   = (unsigned int*)&p_s[0][0];   // row stride 20 dwords

    const int w    = t >> 6;           // wave id
    const int lane = t & 63;
    const int mb = w & 1, nb = w >> 1; // phase A: row-half / hq-half of this wave
    const int lg = lane >> 4;          // 0..3
    const int lm = lane & 15;

    const int rp = t >> 4;             // staging row-pair
    const int cq = (t & 15) << 1;      // staging c offset

    f32x4 o_acc[8][2];                 // [cb][hb]: D rows c=(w*8+cb)*16+4lg+reg, col hq=hb*16+lm
    #pragma unroll
    for (int cb = 0; cb < 8; ++cb) {
        #pragma unroll
        for (int hb = 0; hb < 2; ++hb)
            o_acc[cb][hb] = (f32x4){0.f,0.f,0.f,0.f};
    }
    float l_local = 0.f;

    const size_t xbase = (size_t)b*NN*DIM;
    const uint4* qkB4 = (const uint4*)qkB;

    for (int tile = 0; tile < ntile; ++tile) {
        const int r0 = chunk*crows + tile*TROWS;
        __syncthreads();   // prev tile's phase B done before overwriting Xcm/p_s
        // ---- stage X tile (32 rows x 512 c) as fp16 [c][n] ----
        {
            const float2* Xr0 = (const float2*)(X + xbase + (size_t)(r0 + rp*2    )*DIM);
            const float2* Xr1 = (const float2*)(X + xbase + (size_t)(r0 + rp*2 + 1)*DIM);
            #pragma unroll
            for (int cs = 0; cs < 16; ++cs) {
                int c0 = cs*32 + cq;
                float2 xa = Xr0[c0 >> 1];
                float2 xb = Xr1[c0 >> 1];
                XcmU[c0*18 + rp]     = pkh2(xa.x, xb.x);
                XcmU[(c0+1)*18 + rp] = pkh2(xa.y, xb.y);
            }
        }
        // ---- phase A: S[32r][32hq] = Xtile @ QK via MFMA 16x16x32 f16 ----
        // A-frag: lane holds X[r0+mb*16+lm][kb*32 + lg*8 .. +7] (global; lines warm)
        // D: row n = mb*16 + 4*lg + reg, col hq = nb*16 + lm.
        {
            const float* xr = X + xbase + (size_t)(r0 + mb*16 + lm)*DIM + lg*8;
            f32x4 acc0 = {0.f,0.f,0.f,0.f}, acc1 = {0.f,0.f,0.f,0.f};
            #pragma unroll
            for (int kb = 0; kb < 16; ++kb) {
                float4 a0 = *(const float4*)(xr + kb*32);
                float4 a1 = *(const float4*)(xr + kb*32 + 4);
                U4H8 af;
                af.w[0] = pkh2(a0.x, a0.y); af.w[1] = pkh2(a0.z, a0.w);
                af.w[2] = pkh2(a1.x, a1.y); af.w[3] = pkh2(a1.z, a1.w);
                U4H8 bf; bf.u = qkB4[(size_t)(kb*2 + nb)*64 + lane];
                if (kb & 1) acc1 = __builtin_amdgcn_mfma_f32_16x16x32_f16(af.h, bf.h, acc1, 0, 0, 0);
                else        acc0 = __builtin_amdgcn_mfma_f32_16x16x32_f16(af.h, bf.h, acc0, 0, 0, 0);
            }
            float p0 = __expf(fminf(acc0[0] + acc1[0], 30.f));
            float p1 = __expf(fminf(acc0[1] + acc1[1], 30.f));
            float p2 = __expf(fminf(acc0[2] + acc1[2], 30.f));
            float p3 = __expf(fminf(acc0[3] + acc1[3], 30.f));
            l_local += p0 + p1 + p2 + p3;
            const int pidx = (nb*16 + lm)*20 + mb*8 + lg*2;   // [hq][n] dwords, 8B aligned
            pW[pidx]     = pkh2(p0, p1);
            pW[pidx + 1] = pkh2(p2, p3);
        }
        __syncthreads();
        // ---- phase B: D[c][hq] += X^T @ p via MFMA 16x16x32 f16 (K = n = 32) ----
        // A-frag: lane holds X[n = 8*lg + i][c = (w*8+cb)*16 + lm] = Xcm[c][8lg..8lg+7]
        // B-frag: lane holds p[hq = hb*16 + lm][n = 8*lg + i]      = p_s row (b128)
        {
            U4H8 bf0, bf1;
            const int pbase = lm*20 + lg*4;
            bf0.u = *(const uint4*)&pW[pbase];         // hb = 0
            bf1.u = *(const uint4*)&pW[320 + pbase];   // hb = 1 (16 rows * 20 dw)
            #pragma unroll
            for (int cb = 0; cb < 8; ++cb) {
                const int c = (w*8 + cb)*16 + lm;
                const unsigned int* row = &XcmU[c*18 + lg*4];
                uint2 xa = *(const uint2*)&row[0];
                uint2 xb = *(const uint2*)&row[2];
                U4H8 af;
                af.w[0] = xa.x; af.w[1] = xa.y; af.w[2] = xb.x; af.w[3] = xb.y;
                o_acc[cb][0] = __builtin_amdgcn_mfma_f32_16x16x32_f16(af.h, bf0.h, o_acc[cb][0], 0, 0, 0);
                o_acc[cb][1] = __builtin_amdgcn_mfma_f32_16x16x32_f16(af.h, bf1.h, o_acc[cb][1], 0, 0, 0);
            }
        }
    }
    // ---- block totals ----
    __syncthreads();                   // phase B done: Xcm reusable as transpose buffer
    lred[t] = l_local;
    // transpose o_acc (c-major) -> f16 [32 hq][520 c] in Xcm region
    unsigned int* otU = (unsigned int*)&Xcm[0][0];    // row stride 260 dwords
    #pragma unroll
    for (int cb = 0; cb < 8; ++cb) {
        const int chalf = ((w*8 + cb)*16 + lg*4) >> 1;   // even
        #pragma unroll
        for (int hb = 0; hb < 2; ++hb) {
            const int hq = hb*16 + lm;
            otU[hq*260 + chalf]     = pkh2(o_acc[cb][hb][0], o_acc[cb][hb][1]);
            otU[hq*260 + chalf + 1] = pkh2(o_acc[cb][hb][2], o_acc[cb][hb][3]);
        }
    }
    __syncthreads();
    if (t < 32) {
        const int nb2 = t >> 4, col = t & 15;
        float l = 0.f;
        #pragma unroll
        for (int mm = 0; mm < 2; ++mm)
            #pragma unroll
            for (int g = 0; g < 4; ++g)
                l += lred[(nb2*2 + mm)*64 + g*16 + col];
        lpart[((size_t)b*nchunk + chunk)*HQ + t] = l;
    }
    // coalesced opart write: thread t owns hq = t>>3, c = (t&7)*64 .. +63
    {
        const int hq_w = t >> 3, c0 = (t & 7) << 6;
        const unsigned int* src = &otU[hq_w*260 + (c0 >> 1)];
        f16* dst = opart + (((size_t)b*nchunk + chunk)*HQ + hq_w)*DIM + c0;
        #pragma unroll
        for (int i = 0; i < 4; ++i)
            *(uint4*)(dst + i*16) = *(const uint4*)(src + i*8);
    }
}

// ---------------- K3: reduce partials, normalize, fused Wv slice ----------------
__global__ __launch_bounds__(256) void k_red(
    const f16* __restrict__ opart, const float* __restrict__ lpart,
    const float* __restrict__ Wv, const float* __restrict__ bv,
    float* __restrict__ vbuf, int nchunk)
{
    const int hq = blockIdx.x, b = blockIdx.y;
    const int h = hq >> 2, j = hq & 3;
    const int t = threadIdx.x;
    __shared__ float pool_s[512];
    __shared__ float linv_s;
    if (t < 64) {
        float l = (t < nchunk) ? lpart[((size_t)b*nchunk + t)*HQ + hq] : 0.f;
        #pragma unroll
        for (int m = 1; m < 64; m <<= 1) l += __shfl_xor(l, m);
        if (t == 0) linv_s = 1.f / l;
    }
    float a0 = 0.f, a1 = 0.f;
    const unsigned int* opU = (const unsigned int*)opart;
    #pragma unroll 4
    for (int ch = 0; ch < nchunk; ++ch) {
        unsigned int u = opU[((((size_t)b*nchunk + ch)*HQ + hq) << 8) + t];
        h2_t hv = ash2(u);
        a0 += (float)hv.x; a1 += (float)hv.y;
    }
    __syncthreads();
    float linv = linv_s;
    pool_s[2*t]   = a0 * linv;
    pool_s[2*t+1] = a1 * linv;
    __syncthreads();
    const int o1 = t >> 2, q4 = t & 3;
    const float* wr = Wv + ((size_t)(h*64 + o1))*DIM + q4*128;
    const float* ps = pool_s + q4*128;
    float acc = 0.f;
    #pragma unroll 8
    for (int c = 0; c < 128; c += 4) {
        float4 w4 = *(const float4*)(wr + c);
        float4 p4 = *(const float4*)(ps + c);
        acc += w4.x*p4.x + w4.y*p4.y + w4.z*p4.z + w4.w*p4.w;
    }
    acc += __shfl_xor(acc, 1);
    acc += __shfl_xor(acc, 2);
    if (q4 == 0)
        vbuf[((size_t)b*KQn + j)*DIM + h*64 + o1] = acc + bv[h*64 + o1];
}

// ---------------- K4: Wo proj + residual + LayerNorm ----------------
__global__ __launch_bounds__(512) void k_wo_ln(
    const float* __restrict__ vbuf, const float* __restrict__ Wo, const float* __restrict__ bo,
    const float* __restrict__ seed, const float* __restrict__ gamma, const float* __restrict__ beta,
    float* __restrict__ out)
{
    const int j = blockIdx.x, b = blockIdx.y;
    const int t = threadIdx.x;
    __shared__ float v_s[512];
    __shared__ float wsum[8], wsq[8];
    v_s[t] = vbuf[((size_t)b*KQn + j)*DIM + t];
    __syncthreads();
    const float* wr = Wo + (size_t)t*DIM;
    float acc = bo[t];
    #pragma unroll 8
    for (int c = 0; c < 512; c += 4) {
        float4 w4 = *(const float4*)(wr + c);
        float4 p4 = *(const float4*)&v_s[c];
        acc += w4.x*p4.x + w4.y*p4.y + w4.z*p4.z + w4.w*p4.w;
    }
    float hv = acc + seed[j*DIM + t];
    float s1 = hv, s2 = hv*hv;
    #pragma unroll
    for (int m = 1; m <= 32; m <<= 1) {
        s1 += __shfl_xor(s1, m);
        s2 += __shfl_xor(s2, m);
    }
    if ((t & 63) == 0) { wsum[t >> 6] = s1; wsq[t >> 6] = s2; }
    __syncthreads();
    float tm = 0.f, tq = 0.f;
    #pragma unroll
    for (int i = 0; i < 8; ++i) { tm += wsum[i]; tq += wsq[i]; }
    float mu = tm * (1.f/512.f);
    float var = tq * (1.f/512.f) - mu*mu;
    float rs = rsqrtf(var + EPSLN);
    out[((size_t)b*KQn + j)*DIM + t] = (hv - mu)*rs*gamma[t] + beta[t];
}

extern "C" void kernel_launch(void* const* d_in, const int* in_sizes, int n_in,
                              void* d_out, int out_size, void* d_ws, size_t ws_size,
                              hipStream_t stream) {
    const float* X     = (const float*)d_in[0];
    const float* seed  = (const float*)d_in[1];
    const float* Wq    = (const float*)d_in[2];
    const float* bq    = (const float*)d_in[3];
    const float* Wk    = (const float*)d_in[4];
    // d_in[5] = bk : cancels in softmax, unused
    const float* Wv    = (const float*)d_in[6];
    const float* bv    = (const float*)d_in[7];
    const float* Wo    = (const float*)d_in[8];
    const float* bo    = (const float*)d_in[9];
    const float* gamma = (const float*)d_in[10];
    const float* beta  = (const float*)d_in[11];

    // choose chunk count by available workspace (64 -> 4 blocks/CU occupancy)
    int nchunk = 64;
    {
        const size_t need64 = 303104UL + (size_t)BB*64*HQ*DIM*2;   // ~33.9 MB
        if (ws_size < need64) nchunk = 32;                          // ~17.0 MB fallback
    }
    const int crows = NN / nchunk;
    const int ntile = crows / TROWS;

    char* ws = (char*)d_ws;
    float* q_g   = (float*)(ws + 0);                 //  8192 B
    f16*   qkB   = (f16*)  (ws + 8192);              // 32768 B
    size_t off_lpart = 40960;
    size_t off_vbuf  = off_lpart + (size_t)BB*nchunk*HQ*4;
    size_t off_opart = off_vbuf + (size_t)BB*KQn*DIM*4;
    float* lpart = (float*)(ws + off_lpart);
    float* vbuf  = (float*)(ws + off_vbuf);
    f16*   opart = (f16*)  (ws + off_opart);
    float* out   = (float*)d_out;

    k_q    <<<32,               256, 0, stream>>>(seed, Wq, bq, q_g);
    k_qk   <<<dim3(8, 4),       256, 0, stream>>>(Wk, q_g, qkB);
    k_att  <<<dim3(nchunk, BB), 256, 0, stream>>>(X, qkB, opart, lpart, nchunk, crows, ntile);
    k_red  <<<dim3(HQ, BB),     256, 0, stream>>>(opart, lpart, Wv, bv, vbuf, nchunk);
    k_wo_ln<<<dim3(KQn, BB),    512, 0, stream>>>(vbuf, Wo, bo, seed, gamma, beta, out);
}

// Round 3
// 448.883 us; speedup vs baseline: 1.4863x; 1.1953x over previous
//
#include <hip/hip_runtime.h>
#include <math.h>

#define DIM 512
#define KQn 4
#define HQ  32
#define BB  16
#define NN  8192
#define EPSLN 1e-6f
#define STROWS 16

typedef _Float16 f16;
typedef _Float16 h2_t __attribute__((ext_vector_type(2)));
typedef __fp16   g2_t __attribute__((ext_vector_type(2)));
typedef _Float16 h8_t __attribute__((ext_vector_type(8)));
typedef float    f32x4 __attribute__((ext_vector_type(4)));

union U32H2 { unsigned int u; h2_t h; g2_t g; };
union U4H8  { uint4 u; h8_t h; unsigned int w[4]; };

__device__ inline unsigned int pkh2(float a, float b) {
    U32H2 v; v.g = __builtin_amdgcn_cvt_pkrtz(a, b); return v.u;
}
__device__ inline h2_t ash2(unsigned int u) { U32H2 v; v.u = u; return v.h; }

typedef __attribute__((address_space(3))) unsigned char lds_uc;
typedef __attribute__((address_space(1))) const unsigned char gbl_uc;

__device__ inline void gload_lds16(const float* g, void* l) {
    __builtin_amdgcn_global_load_lds((gbl_uc*)g, (lds_uc*)l, 16, 0, 0);
}

// ---------------- K1a: q[hq][d] = seed[j] @ Wq[head h].T + bq ----------------
__global__ __launch_bounds__(256) void k_q(
    const float* __restrict__ seed, const float* __restrict__ Wq,
    const float* __restrict__ bq, float* __restrict__ q_g)
{
    int hq = blockIdx.x; int h = hq >> 2; int j = hq & 3;
    int t = threadIdx.x;
    __shared__ float qpart[256];
    int d = t >> 2, q4 = t & 3;
    const float* sr = seed + j*DIM + q4*128;
    const float* wr = Wq + (size_t)(h*64 + d)*DIM + q4*128;
    float acc = 0.f;
    for (int c = 0; c < 128; c += 4) {
        float4 s4 = *(const float4*)(sr + c);
        float4 w4 = *(const float4*)(wr + c);
        acc += s4.x*w4.x + s4.y*w4.y + s4.z*w4.z + s4.w*w4.w;
    }
    qpart[t] = acc;
    __syncthreads();
    if (t < 64)
        q_g[hq*64 + t] = qpart[t*4] + qpart[t*4+1] + qpart[t*4+2] + qpart[t*4+3] + bq[h*64 + t];
}

// ---------------- K1b: qkB = MFMA-fragment-packed (q @ Wk_head)/8, fp16 ----------------
// B-fragment for v_mfma_f32_16x16x32_f16: lane l holds B[kb*32 + 8*(l>>4)+i][nb*16 + (l&15)].
__global__ __launch_bounds__(256) void k_qk(
    const float* __restrict__ Wk, const float* __restrict__ q_g, f16* __restrict__ qkB)
{
    const int h = blockIdx.x;    // 0..7
    const int cs = blockIdx.y;   // 0..3
    const int t = threadIdx.x;
    __shared__ float q_s[4][64];
    __shared__ float red2[4][128];
    q_s[t >> 6][t & 63] = q_g[(h*4 + (t >> 6))*64 + (t & 63)];
    __syncthreads();
    const int c = cs*128 + (t & 127);
    const int dh = t >> 7;
    float a0=0.f, a1=0.f, a2=0.f, a3=0.f;
    const float* wb = Wk + ((size_t)(h*64 + dh*32))*DIM + c;
    #pragma unroll 8
    for (int d = 0; d < 32; ++d) {
        float w = wb[(size_t)d*DIM];                // coalesced across lanes
        a0 += q_s[0][dh*32 + d]*w;
        a1 += q_s[1][dh*32 + d]*w;
        a2 += q_s[2][dh*32 + d]*w;
        a3 += q_s[3][dh*32 + d]*w;
    }
    if (dh == 1) {
        red2[0][t & 127] = a0; red2[1][t & 127] = a1;
        red2[2][t & 127] = a2; red2[3][t & 127] = a3;
    }
    __syncthreads();
    if (dh == 0) {
        int ci = t & 127;
        float v[4];
        v[0] = (a0 + red2[0][ci]) * 0.125f;
        v[1] = (a1 + red2[1][ci]) * 0.125f;
        v[2] = (a2 + red2[2][ci]) * 0.125f;
        v[3] = (a3 + red2[3][ci]) * 0.125f;
        const int kb = c >> 5, g = (c >> 3) & 3, ii = c & 7;
        #pragma unroll
        for (int j = 0; j < 4; ++j) {
            const int hq = h*4 + j;
            const int nb = hq >> 4, lane = g*16 + (hq & 15);
            qkB[(((size_t)(kb*2 + nb)*64 + lane) << 3) + ii] = (f16)v[j];
        }
    }
}

// ---------------- K2: async-staged scores(MFMA) -> exp -> pool(MFMA) partials ----------------
// block = (chunk of crows rows, b), 256 threads = 4 waves, wave w = (nb = w&1, kh = w>>1).
// X tile (16 rows x 512) staged ROW-MAJOR fp32 in LDS via global_load_lds (async, zero VGPR),
// with 16B-granule XOR swizzle: phys_granule = logical_granule ^ (row&7), applied by
// pre-swizzling the per-lane GLOBAL source address (LDS dest stays linear).
// Per tile: phase A (scores, kh-split K) -> sred reduce -> exp -> p_s[hq][n] (n>=16 zero)
//        -> issue next-tile stage -> phase B (pool, 16x16x32 with zero-padded upper K).
// LDS 71 KB -> 2 blocks/CU; VGPR cap 256 (2 waves/SIMD) gives pipelining headroom.
__global__ __launch_bounds__(256, 2) void k_att(
    const float* __restrict__ X, const f16* __restrict__ qkB,
    f16* __restrict__ opart, float* __restrict__ lpart,
    int nchunk, int crows, int ntile)
{
    const int chunk = blockIdx.x, b = blockIdx.y;
    const int t = threadIdx.x;

    __shared__ __align__(16) float Xbuf[2][STROWS*512];   // row-major f32, swizzled granules
    __shared__ __align__(16) f16 p_s[32][40];             // [hq][n], n in [0,32), n>=16 == 0
    __shared__ __align__(16) float sred[2][64][4];        // kh=1 partial scores
    __shared__ float lred[256];

    unsigned int* pW = (unsigned int*)&p_s[0][0];         // row stride 20 dwords

    const int w = t >> 6, lane = t & 63;
    const int nb = w & 1, kh = w >> 1;
    const int lg = lane >> 4, lm = lane & 15;

    f32x4 o_acc[8][2];
    #pragma unroll
    for (int cb = 0; cb < 8; ++cb) {
        o_acc[cb][0] = (f32x4){0.f,0.f,0.f,0.f};
        o_acc[cb][1] = (f32x4){0.f,0.f,0.f,0.f};
    }
    float l_local = 0.f;

    const size_t xbase = (size_t)b*NN*DIM;

    // hoist this wave's qkB slice into registers (constant across tiles)
    uint4 bfA[8];
    const uint4* qkB4 = (const uint4*)qkB;
    #pragma unroll
    for (int j = 0; j < 8; ++j)
        bfA[j] = qkB4[(size_t)((kh*8 + j)*2 + nb)*64 + lane];

    // zero p_s upper half (n = 16..31) once
    pW[(t >> 3)*20 + 8 + (t & 7)] = 0u;

    // stage one 16x512 f32 tile into Xbuf[bufi]; wave w covers instrs i = w*8..w*8+7,
    // instr i = row (i>>1), half (i&1); lane's global col granule = half*64 + (lane ^ (row&7))
    #define STAGE(bufi, tile_)                                                          \
    {                                                                                   \
        const int r0s = chunk*crows + (tile_)*STROWS;                                   \
        _Pragma("unroll")                                                               \
        for (int j = 0; j < 8; ++j) {                                                   \
            const int i = w*8 + j;                                                      \
            const int row = i >> 1, half = i & 1;                                       \
            const float* gp = X + xbase + (size_t)(r0s + row)*DIM                       \
                              + ((half*64 + (lane ^ (row & 7))) << 2);                  \
            void* lp = (void*)((char*)&Xbuf[bufi][0] + i*1024);                         \
            gload_lds16(gp, lp);                                                        \
        }                                                                               \
    }

    STAGE(0, 0)
    __syncthreads();          // drains vmcnt(0): tile 0 staged; p_s zeros visible
    int cur = 0;

    for (int tile = 0; tile < ntile; ++tile) {
        const float* xb = &Xbuf[cur][0];
        // ---- phase A: partial S[16 n][16 hq] over kb = kh*8..kh*8+7 (K=32 each) ----
        // A-frag: lane (lg,lm): row lm, c = kb*32 + lg*8..+7  (from swizzled LDS)
        // D: row n = 4*lg + reg, col hq = nb*16 + lm
        f32x4 part;
        {
            f32x4 acc0 = {0.f,0.f,0.f,0.f}, acc1 = {0.f,0.f,0.f,0.f};
            const int swzA = lm & 7;
            const float* rowp = xb + lm*512;
            #pragma unroll
            for (int j = 0; j < 8; ++j) {
                const int kb = kh*8 + j;
                const int pg0 = (kb*8 + lg*2) ^ swzA;     // phys granule of logical g0 (even)
                f32x4 xv0 = *(const f32x4*)(rowp + (pg0 << 2));
                f32x4 xv1 = *(const f32x4*)(rowp + ((pg0 ^ 1) << 2));
                U4H8 af;
                af.w[0] = pkh2(xv0[0], xv0[1]); af.w[1] = pkh2(xv0[2], xv0[3]);
                af.w[2] = pkh2(xv1[0], xv1[1]); af.w[3] = pkh2(xv1[2], xv1[3]);
                U4H8 bf; bf.u = bfA[j];
                if (j & 1) acc1 = __builtin_amdgcn_mfma_f32_16x16x32_f16(af.h, bf.h, acc1, 0, 0, 0);
                else       acc0 = __builtin_amdgcn_mfma_f32_16x16x32_f16(af.h, bf.h, acc0, 0, 0, 0);
            }
            part = acc0 + acc1;
        }
        if (kh == 1) *(f32x4*)&sred[nb][lane][0] = part;
        __syncthreads();
        // ---- reduce kh halves, exp, write p_s (rows n = 4lg..4lg+3, col hq=nb*16+lm) ----
        if (kh == 0) {
            f32x4 o = *(const f32x4*)&sred[nb][lane][0];
            float p0 = __expf(fminf(part[0] + o[0], 30.f));
            float p1 = __expf(fminf(part[1] + o[1], 30.f));
            float p2 = __expf(fminf(part[2] + o[2], 30.f));
            float p3 = __expf(fminf(part[3] + o[3], 30.f));
            l_local += p0 + p1 + p2 + p3;
            const int pidx = (nb*16 + lm)*20 + lg*2;
            pW[pidx]     = pkh2(p0, p1);
            pW[pidx + 1] = pkh2(p2, p3);
        }
        __syncthreads();
        // ---- issue next tile's staging (drains at the end-of-tile barrier) ----
        if (tile + 1 < ntile) STAGE(cur ^ 1, tile + 1)
        // ---- phase B: D[c][hq] += X^T @ p via 16x16x32 (upper 16 k zero-padded) ----
        // A-frag: lane: c = (w*8+cb)*16 + lm, k=n = 8lg+i (n&15 clamped; n>=16 -> b==0)
        // B-frag: p_s row hq = hb*16+lm, dwords 4lg..4lg+3 (n pairs 8lg..8lg+7)
        {
            U4H8 bf0, bf1;
            bf0.u = *(const uint4*)&pW[lm*20 + lg*4];
            bf1.u = *(const uint4*)&pW[(16 + lm)*20 + lg*4];
            #pragma unroll
            for (int cb = 0; cb < 8; ++cb) {
                const int c = (w*8 + cb)*16 + lm;
                const int cg = c >> 2, cr = c & 3;
                float xv[8];
                #pragma unroll
                for (int i = 0; i < 8; ++i) {
                    const int nn = (8*lg + i) & 15;
                    xv[i] = xb[nn*512 + (((cg ^ (nn & 7)) << 2) | cr)];
                }
                U4H8 af;
                af.w[0] = pkh2(xv[0], xv[1]); af.w[1] = pkh2(xv[2], xv[3]);
                af.w[2] = pkh2(xv[4], xv[5]); af.w[3] = pkh2(xv[6], xv[7]);
                o_acc[cb][0] = __builtin_amdgcn_mfma_f32_16x16x32_f16(af.h, bf0.h, o_acc[cb][0], 0, 0, 0);
                o_acc[cb][1] = __builtin_amdgcn_mfma_f32_16x16x32_f16(af.h, bf1.h, o_acc[cb][1], 0, 0, 0);
            }
        }
        __syncthreads();       // drains own stage vmcnt; publishes; Xbuf[cur]/p_s reusable
        cur ^= 1;
    }

    // ---- block totals ----
    lred[t] = l_local;
    // transpose o_acc (c-major) -> f16 [32 hq][520 c] overlaid on Xbuf
    unsigned int* otU = (unsigned int*)&Xbuf[0][0];    // row stride 260 dwords
    #pragma unroll
    for (int cb = 0; cb < 8; ++cb) {
        const int chalf = ((w*8 + cb)*16 + lg*4) >> 1;   // even
        #pragma unroll
        for (int hb = 0; hb < 2; ++hb) {
            const int hq = hb*16 + lm;
            otU[hq*260 + chalf]     = pkh2(o_acc[cb][hb][0], o_acc[cb][hb][1]);
            otU[hq*260 + chalf + 1] = pkh2(o_acc[cb][hb][2], o_acc[cb][hb][3]);
        }
    }
    __syncthreads();
    if (t < 32) {
        float l = 0.f;
        #pragma unroll
        for (int g = 0; g < 4; ++g)
            l += lred[(t >> 4)*64 + g*16 + (t & 15)];
        lpart[((size_t)b*nchunk + chunk)*HQ + t] = l;
    }
    // coalesced opart write: thread t owns hq = t>>3, c = (t&7)*64 .. +63 (full coverage)
    {
        const int hq_w = t >> 3, c0 = (t & 7) << 6;
        const unsigned int* src = &otU[hq_w*260 + (c0 >> 1)];
        f16* dst = opart + (((size_t)b*nchunk + chunk)*HQ + hq_w)*DIM + c0;
        #pragma unroll
        for (int i = 0; i < 8; ++i)
            *(uint4*)(dst + i*8) = *(const uint4*)(src + i*4);
    }
    #undef STAGE
}

// ---------------- K3: reduce partials, normalize, fused Wv slice ----------------
__global__ __launch_bounds__(256) void k_red(
    const f16* __restrict__ opart, const float* __restrict__ lpart,
    const float* __restrict__ Wv, const float* __restrict__ bv,
    float* __restrict__ vbuf, int nchunk)
{
    const int hq = blockIdx.x, b = blockIdx.y;
    const int h = hq >> 2, j = hq & 3;
    const int t = threadIdx.x;
    __shared__ float pool_s[512];
    __shared__ float linv_s;
    if (t < 64) {
        float l = (t < nchunk) ? lpart[((size_t)b*nchunk + t)*HQ + hq] : 0.f;
        #pragma unroll
        for (int m = 1; m < 64; m <<= 1) l += __shfl_xor(l, m);
        if (t == 0) linv_s = 1.f / l;
    }
    float a0 = 0.f, a1 = 0.f;
    const unsigned int* opU = (const unsigned int*)opart;
    #pragma unroll 4
    for (int ch = 0; ch < nchunk; ++ch) {
        unsigned int u = opU[((((size_t)b*nchunk + ch)*HQ + hq) << 8) + t];
        h2_t hv = ash2(u);
        a0 += (float)hv.x; a1 += (float)hv.y;
    }
    __syncthreads();
    float linv = linv_s;
    pool_s[2*t]   = a0 * linv;
    pool_s[2*t+1] = a1 * linv;
    __syncthreads();
    const int o1 = t >> 2, q4 = t & 3;
    const float* wr = Wv + ((size_t)(h*64 + o1))*DIM + q4*128;
    const float* ps = pool_s + q4*128;
    float acc = 0.f;
    #pragma unroll 8
    for (int c = 0; c < 128; c += 4) {
        float4 w4 = *(const float4*)(wr + c);
        float4 p4 = *(const float4*)(ps + c);
        acc += w4.x*p4.x + w4.y*p4.y + w4.z*p4.z + w4.w*p4.w;
    }
    acc += __shfl_xor(acc, 1);
    acc += __shfl_xor(acc, 2);
    if (q4 == 0)
        vbuf[((size_t)b*KQn + j)*DIM + h*64 + o1] = acc + bv[h*64 + o1];
}

// ---------------- K4: Wo proj + residual + LayerNorm ----------------
__global__ __launch_bounds__(512) void k_wo_ln(
    const float* __restrict__ vbuf, const float* __restrict__ Wo, const float* __restrict__ bo,
    const float* __restrict__ seed, const float* __restrict__ gamma, const float* __restrict__ beta,
    float* __restrict__ out)
{
    const int j = blockIdx.x, b = blockIdx.y;
    const int t = threadIdx.x;
    __shared__ float v_s[512];
    __shared__ float wsum[8], wsq[8];
    v_s[t] = vbuf[((size_t)b*KQn + j)*DIM + t];
    __syncthreads();
    const float* wr = Wo + (size_t)t*DIM;
    float acc = bo[t];
    #pragma unroll 8
    for (int c = 0; c < 512; c += 4) {
        float4 w4 = *(const float4*)(wr + c);
        float4 p4 = *(const float4*)&v_s[c];
        acc += w4.x*p4.x + w4.y*p4.y + w4.z*p4.z + w4.w*p4.w;
    }
    float hv = acc + seed[j*DIM + t];
    float s1 = hv, s2 = hv*hv;
    #pragma unroll
    for (int m = 1; m <= 32; m <<= 1) {
        s1 += __shfl_xor(s1, m);
        s2 += __shfl_xor(s2, m);
    }
    if ((t & 63) == 0) { wsum[t >> 6] = s1; wsq[t >> 6] = s2; }
    __syncthreads();
    float tm = 0.f, tq = 0.f;
    #pragma unroll
    for (int i = 0; i < 8; ++i) { tm += wsum[i]; tq += wsq[i]; }
    float mu = tm * (1.f/512.f);
    float var = tq * (1.f/512.f) - mu*mu;
    float rs = rsqrtf(var + EPSLN);
    out[((size_t)b*KQn + j)*DIM + t] = (hv - mu)*rs*gamma[t] + beta[t];
}

extern "C" void kernel_launch(void* const* d_in, const int* in_sizes, int n_in,
                              void* d_out, int out_size, void* d_ws, size_t ws_size,
                              hipStream_t stream) {
    const float* X     = (const float*)d_in[0];
    const float* seed  = (const float*)d_in[1];
    const float* Wq    = (const float*)d_in[2];
    const float* bq    = (const float*)d_in[3];
    const float* Wk    = (const float*)d_in[4];
    // d_in[5] = bk : cancels in softmax, unused
    const float* Wv    = (const float*)d_in[6];
    const float* bv    = (const float*)d_in[7];
    const float* Wo    = (const float*)d_in[8];
    const float* bo    = (const float*)d_in[9];
    const float* gamma = (const float*)d_in[10];
    const float* beta  = (const float*)d_in[11];

    // choose chunk count by available workspace (64 preferred)
    int nchunk = 64;
    {
        const size_t need64 = 303104UL + (size_t)BB*64*HQ*DIM*2;   // ~33.9 MB
        if (ws_size < need64) nchunk = 32;                          // ~17.0 MB fallback
    }
    const int crows = NN / nchunk;
    const int ntile = crows / STROWS;

    char* ws = (char*)d_ws;
    float* q_g   = (float*)(ws + 0);                 //  8192 B
    f16*   qkB   = (f16*)  (ws + 8192);              // 32768 B
    size_t off_lpart = 40960;
    size_t off_vbuf  = off_lpart + (size_t)BB*nchunk*HQ*4;
    size_t off_opart = off_vbuf + (size_t)BB*KQn*DIM*4;
    float* lpart = (float*)(ws + off_lpart);
    float* vbuf  = (float*)(ws + off_vbuf);
    f16*   opart = (f16*)  (ws + off_opart);
    float* out   = (float*)d_out;

    k_q    <<<32,               256, 0, stream>>>(seed, Wq, bq, q_g);
    k_qk   <<<dim3(8, 4),       256, 0, stream>>>(Wk, q_g, qkB);
    k_att  <<<dim3(nchunk, BB), 256, 0, stream>>>(X, qkB, opart, lpart, nchunk, crows, ntile);
    k_red  <<<dim3(HQ, BB),     256, 0, stream>>>(opart, lpart, Wv, bv, vbuf, nchunk);
    k_wo_ln<<<dim3(KQn, BB),    512, 0, stream>>>(vbuf, Wo, bo, seed, gamma, beta, out);
}

// Round 4
// 446.826 us; speedup vs baseline: 1.4931x; 1.0046x over previous
//
#include <hip/hip_runtime.h>
#include <math.h>

#define DIM 512
#define KQn 4
#define HQ  32
#define BB  16
#define NN  8192
#define EPSLN 1e-6f
#define STROWS 16

typedef _Float16 f16;
typedef _Float16 h2_t __attribute__((ext_vector_type(2)));
typedef __fp16   g2_t __attribute__((ext_vector_type(2)));
typedef _Float16 h4_t __attribute__((ext_vector_type(4)));
typedef _Float16 h8_t __attribute__((ext_vector_type(8)));
typedef float    f32x4 __attribute__((ext_vector_type(4)));

union U32H2 { unsigned int u; h2_t h; g2_t g; };
union U2H4  { uint2 u; h4_t h; unsigned int w[2]; };
union U4H8  { uint4 u; h8_t h; unsigned int w[4]; };

__device__ inline unsigned int pkh2(float a, float b) {
    U32H2 v; v.g = __builtin_amdgcn_cvt_pkrtz(a, b); return v.u;
}
__device__ inline h2_t ash2(unsigned int u) { U32H2 v; v.u = u; return v.h; }

typedef __attribute__((address_space(3))) unsigned char lds_uc;
typedef __attribute__((address_space(1))) const unsigned char gbl_uc;

__device__ inline void gload_lds16(const float* g, void* l) {
    __builtin_amdgcn_global_load_lds((gbl_uc*)g, (lds_uc*)l, 16, 0, 0);
}

// ---------------- K1a: q[hq][d] = seed[j] @ Wq[head h].T + bq ----------------
__global__ __launch_bounds__(256) void k_q(
    const float* __restrict__ seed, const float* __restrict__ Wq,
    const float* __restrict__ bq, float* __restrict__ q_g)
{
    int hq = blockIdx.x; int h = hq >> 2; int j = hq & 3;
    int t = threadIdx.x;
    __shared__ float qpart[256];
    int d = t >> 2, q4 = t & 3;
    const float* sr = seed + j*DIM + q4*128;
    const float* wr = Wq + (size_t)(h*64 + d)*DIM + q4*128;
    float acc = 0.f;
    for (int c = 0; c < 128; c += 4) {
        float4 s4 = *(const float4*)(sr + c);
        float4 w4 = *(const float4*)(wr + c);
        acc += s4.x*w4.x + s4.y*w4.y + s4.z*w4.z + s4.w*w4.w;
    }
    qpart[t] = acc;
    __syncthreads();
    if (t < 64)
        q_g[hq*64 + t] = qpart[t*4] + qpart[t*4+1] + qpart[t*4+2] + qpart[t*4+3] + bq[h*64 + t];
}

// ---------------- K1b: qkB = MFMA-fragment-packed (q @ Wk_head)/8, fp16 ----------------
// B-fragment for v_mfma_f32_16x16x32_f16: lane l holds B[kb*32 + 8*(l>>4)+i][nb*16 + (l&15)].
__global__ __launch_bounds__(256) void k_qk(
    const float* __restrict__ Wk, const float* __restrict__ q_g, f16* __restrict__ qkB)
{
    const int h = blockIdx.x;    // 0..7
    const int cs = blockIdx.y;   // 0..3
    const int t = threadIdx.x;
    __shared__ float q_s[4][64];
    __shared__ float red2[4][128];
    q_s[t >> 6][t & 63] = q_g[(h*4 + (t >> 6))*64 + (t & 63)];
    __syncthreads();
    const int c = cs*128 + (t & 127);
    const int dh = t >> 7;
    float a0=0.f, a1=0.f, a2=0.f, a3=0.f;
    const float* wb = Wk + ((size_t)(h*64 + dh*32))*DIM + c;
    #pragma unroll 8
    for (int d = 0; d < 32; ++d) {
        float w = wb[(size_t)d*DIM];                // coalesced across lanes
        a0 += q_s[0][dh*32 + d]*w;
        a1 += q_s[1][dh*32 + d]*w;
        a2 += q_s[2][dh*32 + d]*w;
        a3 += q_s[3][dh*32 + d]*w;
    }
    if (dh == 1) {
        red2[0][t & 127] = a0; red2[1][t & 127] = a1;
        red2[2][t & 127] = a2; red2[3][t & 127] = a3;
    }
    __syncthreads();
    if (dh == 0) {
        int ci = t & 127;
        float v[4];
        v[0] = (a0 + red2[0][ci]) * 0.125f;
        v[1] = (a1 + red2[1][ci]) * 0.125f;
        v[2] = (a2 + red2[2][ci]) * 0.125f;
        v[3] = (a3 + red2[3][ci]) * 0.125f;
        const int kb = c >> 5, g = (c >> 3) & 3, ii = c & 7;
        #pragma unroll
        for (int j = 0; j < 4; ++j) {
            const int hq = h*4 + j;
            const int nb = hq >> 4, lane = g*16 + (hq & 15);
            qkB[(((size_t)(kb*2 + nb)*64 + lane) << 3) + ii] = (f16)v[j];
        }
    }
}

// ---------------- K2: async-staged scores(MFMA) -> exp -> pool(MFMA x16) partials ----------------
// block = (chunk of crows rows, b), 256 threads = 4 waves, wave w = (nb = w&1, kh = w>>1).
// X tile (16 rows x 512) staged ROW-MAJOR fp32 in LDS via global_load_lds (async, zero VGPR),
// with 16B-granule XOR swizzle: phys_granule = logical_granule ^ (row&7), applied by
// pre-swizzling the per-lane GLOBAL source address (LDS dest stays linear).
// Per tile: issue next-tile stage (drains at end-of-tile barrier -> full-tile latency window)
//        -> phase A (scores, kh-split K) -> sred reduce -> exp -> p_s[hq][n], n in [0,16)
//        -> phase B (pool, v_mfma_f32_16x16x16f16, exact K=16, no padding waste).
// LDS ~70 KB -> 2 blocks/CU.
__global__ __launch_bounds__(256, 2) void k_att(
    const float* __restrict__ X, const f16* __restrict__ qkB,
    f16* __restrict__ opart, float* __restrict__ lpart,
    int nchunk, int crows, int ntile)
{
    const int chunk = blockIdx.x, b = blockIdx.y;
    const int t = threadIdx.x;

    __shared__ __align__(16) float Xbuf[2][STROWS*512];   // row-major f32, swizzled granules
    __shared__ __align__(16) f16 p_s[32][40];             // [hq][n], n in [0,16) used
    __shared__ __align__(16) float sred[2][64][4];        // kh=1 partial scores
    __shared__ float lred[256];

    unsigned int* pW = (unsigned int*)&p_s[0][0];         // row stride 20 dwords

    const int w = t >> 6, lane = t & 63;
    const int nb = w & 1, kh = w >> 1;
    const int lg = lane >> 4, lm = lane & 15;

    f32x4 o_acc[8][2];
    #pragma unroll
    for (int cb = 0; cb < 8; ++cb) {
        o_acc[cb][0] = (f32x4){0.f,0.f,0.f,0.f};
        o_acc[cb][1] = (f32x4){0.f,0.f,0.f,0.f};
    }
    float l_local = 0.f;

    const size_t xbase = (size_t)b*NN*DIM;

    // hoist this wave's qkB slice into registers (constant across tiles)
    uint4 bfA[8];
    const uint4* qkB4 = (const uint4*)qkB;
    #pragma unroll
    for (int j = 0; j < 8; ++j)
        bfA[j] = qkB4[(size_t)((kh*8 + j)*2 + nb)*64 + lane];

    // stage one 16x512 f32 tile into Xbuf[bufi]; wave w covers instrs i = w*8..w*8+7,
    // instr i = row (i>>1), half (i&1); lane's global col granule = half*64 + (lane ^ (row&7))
    #define STAGE(bufi, tile_)                                                          \
    {                                                                                   \
        const int r0s = chunk*crows + (tile_)*STROWS;                                   \
        _Pragma("unroll")                                                               \
        for (int j = 0; j < 8; ++j) {                                                   \
            const int i = w*8 + j;                                                      \
            const int row = i >> 1, half = i & 1;                                       \
            const float* gp = X + xbase + (size_t)(r0s + row)*DIM                       \
                              + ((half*64 + (lane ^ (row & 7))) << 2);                  \
            void* lp = (void*)((char*)&Xbuf[bufi][0] + i*1024);                         \
            gload_lds16(gp, lp);                                                        \
        }                                                                               \
    }

    STAGE(0, 0)
    __syncthreads();          // drains vmcnt(0): tile 0 staged
    int cur = 0;

    for (int tile = 0; tile < ntile; ++tile) {
        // ---- issue next tile's staging NOW: in-flight across the whole tile ----
        if (tile + 1 < ntile) STAGE(cur ^ 1, tile + 1)
        const float* xb = &Xbuf[cur][0];
        // ---- phase A: partial S[16 n][16 hq] over kb = kh*8..kh*8+7 (K=32 each) ----
        // A-frag: lane (lg,lm): row lm, c = kb*32 + lg*8..+7  (from swizzled LDS)
        // D: row n = 4*lg + reg, col hq = nb*16 + lm
        f32x4 part;
        {
            f32x4 acc0 = {0.f,0.f,0.f,0.f}, acc1 = {0.f,0.f,0.f,0.f};
            const int swzA = lm & 7;
            const float* rowp = xb + lm*512;
            #pragma unroll
            for (int j = 0; j < 8; ++j) {
                const int kb = kh*8 + j;
                const int pg0 = (kb*8 + lg*2) ^ swzA;     // phys granule of logical g0 (even)
                f32x4 xv0 = *(const f32x4*)(rowp + (pg0 << 2));
                f32x4 xv1 = *(const f32x4*)(rowp + ((pg0 ^ 1) << 2));
                U4H8 af;
                af.w[0] = pkh2(xv0[0], xv0[1]); af.w[1] = pkh2(xv0[2], xv0[3]);
                af.w[2] = pkh2(xv1[0], xv1[1]); af.w[3] = pkh2(xv1[2], xv1[3]);
                U4H8 bf; bf.u = bfA[j];
                if (j & 1) acc1 = __builtin_amdgcn_mfma_f32_16x16x32_f16(af.h, bf.h, acc1, 0, 0, 0);
                else       acc0 = __builtin_amdgcn_mfma_f32_16x16x32_f16(af.h, bf.h, acc0, 0, 0, 0);
            }
            part = acc0 + acc1;
        }
        if (kh == 1) *(f32x4*)&sred[nb][lane][0] = part;
        __syncthreads();
        // ---- reduce kh halves, exp, write p_s (rows n = 4lg..4lg+3, col hq=nb*16+lm) ----
        if (kh == 0) {
            f32x4 o = *(const f32x4*)&sred[nb][lane][0];
            float p0 = __expf(fminf(part[0] + o[0], 30.f));
            float p1 = __expf(fminf(part[1] + o[1], 30.f));
            float p2 = __expf(fminf(part[2] + o[2], 30.f));
            float p3 = __expf(fminf(part[3] + o[3], 30.f));
            l_local += p0 + p1 + p2 + p3;
            const int pidx = (nb*16 + lm)*20 + lg*2;
            pW[pidx]     = pkh2(p0, p1);
            pW[pidx + 1] = pkh2(p2, p3);
        }
        __syncthreads();
        // ---- phase B: D[c][hq] += X^T @ p via v_mfma_f32_16x16x16f16 (K = 16 exact) ----
        // A-frag: lane (lg,lm): row c = (w*8+cb)*16 + lm, k = n = 4*lg + i, i=0..3
        // B-frag: lane: B[k = 4lg+i][col hq = hb*16+lm] = p_s[hq] halves 4lg..4lg+3 (b64)
        // D: row (c-offset) = 4*lg + reg, col hq = hb*16 + lm
        {
            U2H4 bf0, bf1;
            bf0.u = *(const uint2*)&pW[lm*20 + lg*2];
            bf1.u = *(const uint2*)&pW[(16 + lm)*20 + lg*2];
            #pragma unroll
            for (int cb = 0; cb < 8; ++cb) {
                const int c = (w*8 + cb)*16 + lm;
                const int cg = c >> 2, cr = c & 3;
                float xv[4];
                #pragma unroll
                for (int i = 0; i < 4; ++i) {
                    const int nn = 4*lg + i;
                    xv[i] = xb[nn*512 + (((cg ^ (nn & 7)) << 2) | cr)];
                }
                U2H4 af;
                af.w[0] = pkh2(xv[0], xv[1]); af.w[1] = pkh2(xv[2], xv[3]);
                o_acc[cb][0] = __builtin_amdgcn_mfma_f32_16x16x16f16(af.h, bf0.h, o_acc[cb][0], 0, 0, 0);
                o_acc[cb][1] = __builtin_amdgcn_mfma_f32_16x16x16f16(af.h, bf1.h, o_acc[cb][1], 0, 0, 0);
            }
        }
        __syncthreads();       // drains next-tile stage vmcnt; Xbuf[cur]/p_s reusable
        cur ^= 1;
    }

    // ---- block totals ----
    lred[t] = l_local;
    // transpose o_acc (c-major) -> f16 [32 hq][520 c] overlaid on Xbuf
    unsigned int* otU = (unsigned int*)&Xbuf[0][0];    // row stride 260 dwords
    #pragma unroll
    for (int cb = 0; cb < 8; ++cb) {
        const int chalf = ((w*8 + cb)*16 + lg*4) >> 1;   // even
        #pragma unroll
        for (int hb = 0; hb < 2; ++hb) {
            const int hq = hb*16 + lm;
            otU[hq*260 + chalf]     = pkh2(o_acc[cb][hb][0], o_acc[cb][hb][1]);
            otU[hq*260 + chalf + 1] = pkh2(o_acc[cb][hb][2], o_acc[cb][hb][3]);
        }
    }
    __syncthreads();
    if (t < 32) {
        float l = 0.f;
        #pragma unroll
        for (int g = 0; g < 4; ++g)
            l += lred[(t >> 4)*64 + g*16 + (t & 15)];
        lpart[((size_t)b*nchunk + chunk)*HQ + t] = l;
    }
    // coalesced opart write: thread t owns hq = t>>3, c = (t&7)*64 .. +63 (full coverage)
    {
        const int hq_w = t >> 3, c0 = (t & 7) << 6;
        const unsigned int* src = &otU[hq_w*260 + (c0 >> 1)];
        f16* dst = opart + (((size_t)b*nchunk + chunk)*HQ + hq_w)*DIM + c0;
        #pragma unroll
        for (int i = 0; i < 8; ++i)
            *(uint4*)(dst + i*8) = *(const uint4*)(src + i*4);
    }
    #undef STAGE
}

// ---------------- K3: reduce partials, normalize, fused Wv slice ----------------
__global__ __launch_bounds__(256) void k_red(
    const f16* __restrict__ opart, const float* __restrict__ lpart,
    const float* __restrict__ Wv, const float* __restrict__ bv,
    float* __restrict__ vbuf, int nchunk)
{
    const int hq = blockIdx.x, b = blockIdx.y;
    const int h = hq >> 2, j = hq & 3;
    const int t = threadIdx.x;
    __shared__ float pool_s[512];
    __shared__ float linv_s;
    if (t < 64) {
        float l = (t < nchunk) ? lpart[((size_t)b*nchunk + t)*HQ + hq] : 0.f;
        #pragma unroll
        for (int m = 1; m < 64; m <<= 1) l += __shfl_xor(l, m);
        if (t == 0) linv_s = 1.f / l;
    }
    float a0 = 0.f, a1 = 0.f;
    const unsigned int* opU = (const unsigned int*)opart;
    #pragma unroll 4
    for (int ch = 0; ch < nchunk; ++ch) {
        unsigned int u = opU[((((size_t)b*nchunk + ch)*HQ + hq) << 8) + t];
        h2_t hv = ash2(u);
        a0 += (float)hv.x; a1 += (float)hv.y;
    }
    __syncthreads();
    float linv = linv_s;
    pool_s[2*t]   = a0 * linv;
    pool_s[2*t+1] = a1 * linv;
    __syncthreads();
    const int o1 = t >> 2, q4 = t & 3;
    const float* wr = Wv + ((size_t)(h*64 + o1))*DIM + q4*128;
    const float* ps = pool_s + q4*128;
    float acc = 0.f;
    #pragma unroll 8
    for (int c = 0; c < 128; c += 4) {
        float4 w4 = *(const float4*)(wr + c);
        float4 p4 = *(const float4*)(ps + c);
        acc += w4.x*p4.x + w4.y*p4.y + w4.z*p4.z + w4.w*p4.w;
    }
    acc += __shfl_xor(acc, 1);
    acc += __shfl_xor(acc, 2);
    if (q4 == 0)
        vbuf[((size_t)b*KQn + j)*DIM + h*64 + o1] = acc + bv[h*64 + o1];
}

// ---------------- K4: Wo proj + residual + LayerNorm ----------------
__global__ __launch_bounds__(512) void k_wo_ln(
    const float* __restrict__ vbuf, const float* __restrict__ Wo, const float* __restrict__ bo,
    const float* __restrict__ seed, const float* __restrict__ gamma, const float* __restrict__ beta,
    float* __restrict__ out)
{
    const int j = blockIdx.x, b = blockIdx.y;
    const int t = threadIdx.x;
    __shared__ float v_s[512];
    __shared__ float wsum[8], wsq[8];
    v_s[t] = vbuf[((size_t)b*KQn + j)*DIM + t];
    __syncthreads();
    const float* wr = Wo + (size_t)t*DIM;
    float acc = bo[t];
    #pragma unroll 8
    for (int c = 0; c < 512; c += 4) {
        float4 w4 = *(const float4*)(wr + c);
        float4 p4 = *(const float4*)&v_s[c];
        acc += w4.x*p4.x + w4.y*p4.y + w4.z*p4.z + w4.w*p4.w;
    }
    float hv = acc + seed[j*DIM + t];
    float s1 = hv, s2 = hv*hv;
    #pragma unroll
    for (int m = 1; m <= 32; m <<= 1) {
        s1 += __shfl_xor(s1, m);
        s2 += __shfl_xor(s2, m);
    }
    if ((t & 63) == 0) { wsum[t >> 6] = s1; wsq[t >> 6] = s2; }
    __syncthreads();
    float tm = 0.f, tq = 0.f;
    #pragma unroll
    for (int i = 0; i < 8; ++i) { tm += wsum[i]; tq += wsq[i]; }
    float mu = tm * (1.f/512.f);
    float var = tq * (1.f/512.f) - mu*mu;
    float rs = rsqrtf(var + EPSLN);
    out[((size_t)b*KQn + j)*DIM + t] = (hv - mu)*rs*gamma[t] + beta[t];
}

extern "C" void kernel_launch(void* const* d_in, const int* in_sizes, int n_in,
                              void* d_out, int out_size, void* d_ws, size_t ws_size,
                              hipStream_t stream) {
    const float* X     = (const float*)d_in[0];
    const float* seed  = (const float*)d_in[1];
    const float* Wq    = (const float*)d_in[2];
    const float* bq    = (const float*)d_in[3];
    const float* Wk    = (const float*)d_in[4];
    // d_in[5] = bk : cancels in softmax, unused
    const float* Wv    = (const float*)d_in[6];
    const float* bv    = (const float*)d_in[7];
    const float* Wo    = (const float*)d_in[8];
    const float* bo    = (const float*)d_in[9];
    const float* gamma = (const float*)d_in[10];
    const float* beta  = (const float*)d_in[11];

    // choose chunk count by available workspace (64 preferred)
    int nchunk = 64;
    {
        const size_t need64 = 303104UL + (size_t)BB*64*HQ*DIM*2;   // ~33.9 MB
        if (ws_size < need64) nchunk = 32;                          // ~17.0 MB fallback
    }
    const int crows = NN / nchunk;
    const int ntile = crows / STROWS;

    char* ws = (char*)d_ws;
    float* q_g   = (float*)(ws + 0);                 //  8192 B
    f16*   qkB   = (f16*)  (ws + 8192);              // 32768 B
    size_t off_lpart = 40960;
    size_t off_vbuf  = off_lpart + (size_t)BB*nchunk*HQ*4;
    size_t off_opart = off_vbuf + (size_t)BB*KQn*DIM*4;
    float* lpart = (float*)(ws + off_lpart);
    float* vbuf  = (float*)(ws + off_vbuf);
    f16*   opart = (f16*)  (ws + off_opart);
    float* out   = (float*)d_out;

    k_q    <<<32,               256, 0, stream>>>(seed, Wq, bq, q_g);
    k_qk   <<<dim3(8, 4),       256, 0, stream>>>(Wk, q_g, qkB);
    k_att  <<<dim3(nchunk, BB), 256, 0, stream>>>(X, qkB, opart, lpart, nchunk, crows, ntile);
    k_red  <<<dim3(HQ, BB),     256, 0, stream>>>(opart, lpart, Wv, bv, vbuf, nchunk);
    k_wo_ln<<<dim3(KQn, BB),    512, 0, stream>>>(vbuf, Wo, bo, seed, gamma, beta, out);
}